// Round 6
// baseline (250.924 us; speedup 1.0000x reference)
//
#include <hip/hip_runtime.h>
#include <stdint.h>

typedef unsigned short u16;
typedef __bf16 bf16x8 __attribute__((ext_vector_type(8)));
typedef float f32x4 __attribute__((ext_vector_type(4)));
typedef float f32x16 __attribute__((ext_vector_type(16)));

#define TOKENS 4096
#define SEQLEN 2048
#define EMB 1024
#define NHEADS 16

static constexpr float LAMBDA_INIT_F = 0.7836057665316245f;   // 0.8 - 0.6*exp(-3.6)
static constexpr float ONE_MINUS_LI  = 0.21639423346837553f;
static constexpr float SCALE_F       = 0.17677669529663687f;  // 32^-0.5
static constexpr float LOG2E_F       = 1.4426950408889634f;
static constexpr float INV2PI_F      = 0.15915494309189535f;

__device__ __forceinline__ u16 f2bf(float f) {
  uint32_t u = __builtin_bit_cast(uint32_t, f);
  u += 0x7fffu + ((u >> 16) & 1u);
  return (u16)(u >> 16);
}
__device__ __forceinline__ float bf2f(u16 h) {
  uint32_t u = ((uint32_t)h) << 16;
  return __builtin_bit_cast(float, u);
}
__device__ __forceinline__ float fast_exp2(float x) {
#if __has_builtin(__builtin_amdgcn_exp2f)
  return __builtin_amdgcn_exp2f(x);
#else
  return exp2f(x);
#endif
}
__device__ __forceinline__ void async16(const void* g, void* l) {
  __builtin_amdgcn_global_load_lds((__attribute__((address_space(1))) void*)(g),
                                   (__attribute__((address_space(3))) void*)(l),
                                   16, 0, 0);
}
__device__ __forceinline__ f32x4 mfma16(uint4 a, uint4 b, f32x4 c) {
  return __builtin_amdgcn_mfma_f32_16x16x32_bf16(
      __builtin_bit_cast(bf16x8, a), __builtin_bit_cast(bf16x8, b), c, 0, 0, 0);
}
__device__ __forceinline__ f32x16 mfma32(uint4 a, uint4 b, f32x16 c) {
  return __builtin_amdgcn_mfma_f32_32x32x16_bf16(
      __builtin_bit_cast(bf16x8, a), __builtin_bit_cast(bf16x8, b), c, 0, 0, 0);
}

// ---------------------------------------------------------------------------
// prep: fp32 -> bf16 for x, Wq, Wk, Wv, Wo; compute lam scalar.
// ---------------------------------------------------------------------------
__global__ __launch_bounds__(256) void prep_kernel(
    const float* __restrict__ x,  const float* __restrict__ wq,
    const float* __restrict__ wk, const float* __restrict__ wv,
    const float* __restrict__ wo, const float* __restrict__ lq1,
    const float* __restrict__ lk1,const float* __restrict__ lq2,
    const float* __restrict__ lk2,
    u16* __restrict__ xb, u16* __restrict__ wqb, u16* __restrict__ wkb,
    u16* __restrict__ wvb, u16* __restrict__ wob, float* __restrict__ lam_out)
{
  int i0 = (blockIdx.x * 256 + threadIdx.x) * 4;
  const float* src; u16* dst; int j;
  if (i0 < 4194304)      { src = x;  dst = xb;  j = i0; }
  else if (i0 < 5242880) { src = wq; dst = wqb; j = i0 - 4194304; }
  else if (i0 < 6291456) { src = wk; dst = wkb; j = i0 - 5242880; }
  else if (i0 < 7340032) { src = wv; dst = wvb; j = i0 - 6291456; }
  else                   { src = wo; dst = wob; j = i0 - 7340032; }
  float4 v = *(const float4*)(src + j);
  uint2 pack;
  pack.x = (uint32_t)f2bf(v.x) | ((uint32_t)f2bf(v.y) << 16);
  pack.y = (uint32_t)f2bf(v.z) | ((uint32_t)f2bf(v.w) << 16);
  *(uint2*)(dst + j) = pack;

  if (blockIdx.x == 0 && threadIdx.x == 0) {
    float d1 = 0.f, d2 = 0.f;
    for (int i = 0; i < 32; ++i) { d1 += lq1[i] * lk1[i]; d2 += lq2[i] * lk2[i]; }
    *lam_out = expf(d1) - expf(d2) + LAMBDA_INIT_F;
  }
}

// ---------------------------------------------------------------------------
// GEMM: C(4096x1024) = A(4096x1024,bf16) * B^T (B is 1024x1024 N-major, bf16)
// 128x128 block tile, BK=64, 4 waves each 64x64, 16x16x32 bf16 MFMA.
// LDS XOR-swizzled (16B chunk ^= row&7) to kill 128B-stride bank conflicts.
// MODE: 0 = q out (fused RoPE + SCALE*log2e, bf16)
//       1 = f32 row-major C
//       2 = bf16 V^T [b][h][d][key]
//       3 = k out (fused RoPE, bf16)
// RoPE fusion: lane holds channel col for 4 tokens; partner channel col^1 is
// one quad-perm __shfl_xor(v,1) away. sin/cos via v_sin/cos_f32 (revolutions,
// v_fract range reduction).
// ---------------------------------------------------------------------------
template <int MODE>
__device__ __forceinline__ void gemm_body(const u16* __restrict__ A,
                                          const u16* __restrict__ B,
                                          void* __restrict__ C)
{
  __shared__ u16 As[128 * 64];
  __shared__ u16 Bs[128 * 64];
  const int t = threadIdx.x;
  const int lane = t & 63, w = t >> 6;
  const int q4 = lane >> 4, lm = lane & 15;
  const int wr = w >> 1, wc = w & 1;
  const int bm = blockIdx.y * 128, bn = blockIdx.x * 128;

  f32x4 acc[4][4];
#pragma unroll
  for (int mi = 0; mi < 4; ++mi)
#pragma unroll
    for (int ni = 0; ni < 4; ++ni) acc[mi][ni] = (f32x4){0.f, 0.f, 0.f, 0.f};

  for (int kt = 0; kt < 16; ++kt) {
    const int k0 = kt * 64;
    __syncthreads();  // previous tile's LDS reads complete
#pragma unroll
    for (int ro = 0; ro < 4; ++ro) {
      int ft = ro * 256 + t;
      int row = ft >> 3;
      int col = (((ft & 7) ^ (row & 7)) << 3);   // source chunk permuted = XOR swizzle
      async16(&A[(bm + row) * 1024 + k0 + col], &As[ft * 8]);
      async16(&B[(bn + row) * 1024 + k0 + col], &Bs[ft * 8]);
    }
    __syncthreads();  // drains vmcnt -> LDS visible
#pragma unroll
    for (int ks = 0; ks < 2; ++ks) {
      uint4 af[4], bf[4];
#pragma unroll
      for (int mi = 0; mi < 4; ++mi)
        af[mi] = *(const uint4*)&As[(wr * 64 + mi * 16 + lm) * 64 +
                                    (((ks * 4 + q4) ^ (lm & 7)) << 3)];
#pragma unroll
      for (int ni = 0; ni < 4; ++ni)
        bf[ni] = *(const uint4*)&Bs[(wc * 64 + ni * 16 + lm) * 64 +
                                    (((ks * 4 + q4) ^ (lm & 7)) << 3)];
#pragma unroll
      for (int mi = 0; mi < 4; ++mi)
#pragma unroll
        for (int ni = 0; ni < 4; ++ni)
          acc[mi][ni] = mfma16(af[mi], bf[ni], acc[mi][ni]);
    }
  }

  if (MODE == 0 || MODE == 3) {
    // fused RoPE epilogue. j (freq idx) = (col>>1)&15 = (ni&1)*8 + (lm>>1).
    float angrev[2];
    angrev[0] = exp2f(-(float)(lm >> 1) * 0.8858474919699633f) * INV2PI_F;
    angrev[1] = exp2f(-(float)(8 + (lm >> 1)) * 0.8858474919699633f) * INV2PI_F;
    const bool oddc = (lm & 1);
    const float qsc = (MODE == 0) ? (SCALE_F * LOG2E_F) : 1.f;
#pragma unroll
    for (int mi = 0; mi < 4; ++mi)
#pragma unroll
      for (int r = 0; r < 4; ++r) {
        int row = bm + wr * 64 + mi * 16 + q4 * 4 + r;
        float tf = (float)(row & (SEQLEN - 1));
        float sv[2], cv[2];
#pragma unroll
        for (int p = 0; p < 2; ++p) {
          float prod = tf * angrev[p];
          float fr = prod - floorf(prod);
          sv[p] = __builtin_amdgcn_sinf(fr);
          cv[p] = __builtin_amdgcn_cosf(fr);
        }
#pragma unroll
        for (int ni = 0; ni < 4; ++ni) {
          float v = acc[mi][ni][r];
          float pv = __shfl_xor(v, 1);
          int p = ni & 1;
          float o = oddc ? (pv * sv[p] + v * cv[p]) : (v * cv[p] - pv * sv[p]);
          o *= qsc;
          int col = bn + wc * 64 + ni * 16 + lm;
          ((u16*)C)[row * 1024 + col] = f2bf(o);
        }
      }
  } else {
#pragma unroll
    for (int mi = 0; mi < 4; ++mi)
#pragma unroll
      for (int ni = 0; ni < 4; ++ni) {
        if (MODE == 2) {
          // V^T: rows of C are tokens, cols are channels; write vt[b][h][d][key]
          int token0 = bm + wr * 64 + mi * 16 + q4 * 4;     // 4 consecutive tokens
          int col = bn + wc * 64 + ni * 16 + lm;            // channel 0..1023
          int bb = token0 >> 11, key0 = token0 & 2047;
          int h = col >> 6, d = col & 63;
          ushort4 pk;
          pk.x = f2bf(acc[mi][ni][0]);
          pk.y = f2bf(acc[mi][ni][1]);
          pk.z = f2bf(acc[mi][ni][2]);
          pk.w = f2bf(acc[mi][ni][3]);
          *(ushort4*)((u16*)C + ((size_t)((bb * 16 + h) * 64 + d)) * 2048 + key0) = pk;
        } else {
#pragma unroll
          for (int r = 0; r < 4; ++r) {
            int row = bm + wr * 64 + mi * 16 + q4 * 4 + r;
            int col = bn + wc * 64 + ni * 16 + lm;
            ((float*)C)[row * 1024 + col] = acc[mi][ni][r];
          }
        }
      }
  }
}

__global__ __launch_bounds__(256) void gemm_qkv_kernel(
    const u16* __restrict__ xb, const u16* __restrict__ wqb,
    const u16* __restrict__ wkb, const u16* __restrict__ wvb,
    u16* __restrict__ qb, u16* __restrict__ kb, u16* __restrict__ vtb)
{
  if (blockIdx.z == 0)      gemm_body<0>(xb, wqb, qb);
  else if (blockIdx.z == 1) gemm_body<3>(xb, wkb, kb);
  else                      gemm_body<2>(xb, wvb, vtb);
}

// Output GEMM: proven 128x128 config (rounds 1-4). 64x128 split regressed
// (1.5x staging rows, half the MFMA amortizing each barrier drain).
__global__ __launch_bounds__(256) void gemm_out_kernel(
    const u16* __restrict__ ab, const u16* __restrict__ wob,
    float* __restrict__ out)
{
  gemm_body<1>(ab, wob, out);
}

// ---------------------------------------------------------------------------
// Fused differential flash attention + RMS-norm epilogue.
// Block = (64-row Q tile, head, batch); 4 waves specialized as
// (component c = w>>1, rowgroup rg = w&1), each wave owns 32 q-rows x 1 comp.
// S^T = mfma32(K_frag, Q_frag): lane's C-column = its q-row, 16 keys in-lane.
// exp2 + v_perm-pack to bf16, then the PV B-operand (P^T) is assembled
// IN REGISTERS via __shfl_xor(32) with the partner lane (no LDS round-trip).
// PV: O^T = mfma32(V^T A-frag, P^T B-frag) -> lane's O column = its q-row,
// so softmax denominators are per-lane scalars and RMS-norm is one shfl.
// Component combine via one 16KB LDS exchange at epilogue.
// LDS 16KB: Ks [0,4096) u16, Vt [4096,8192) u16, both XOR-swizzled; the same
// space is reused for the f32 epilogue exchange and the pre-loop Q stage.
// z16: persistent zero C-operand so S's first MFMA doesn't re-zero 16 VGPRs
// per iteration (was ~13% of loop VALU).
// ---------------------------------------------------------------------------
__global__ __launch_bounds__(256, 4) void attn_kernel(
    const u16* __restrict__ qb, const u16* __restrict__ kb,
    const u16* __restrict__ vtb, const float* __restrict__ lam_p,
    const float* __restrict__ rmsw, u16* __restrict__ ab)
{
  __shared__ u16 smem[8192];

  const int t = threadIdx.x;
  const int lane = t & 63, w = t >> 6;
  const int l5 = lane >> 5, lr = lane & 31;
  const int c = w >> 1, rg = w & 1;
  const bool hi = (l5 != 0);
  const int qt = blockIdx.x, h = blockIdx.y, b = blockIdx.z;
  const int tok0 = b * SEQLEN + qt * 64;
  const int hch = h * 64;

  const u16* kbase = kb + (size_t)(b * SEQLEN) * 1024 + hch;
  const u16* vbase = vtb + (size_t)((b * 16 + h) * 64) * 2048;

  // stage Q tile (64 rows x 64 ch) into Ks region, swizzled
#pragma unroll
  for (int ro = 0; ro < 2; ++ro) {
    int ft = ro * 256 + t;
    int row = ft >> 3;
    int col = (((ft & 7) ^ (row & 7)) << 3);
    async16(&qb[(tok0 + row) * 1024 + hch + col], &smem[ft * 8]);
  }
  __syncthreads();
  uint4 qf[2];   // B-frags for comp c: Q[qrow=rg*32+lr][c*32 + kk*16 + l5*8 + j]
#pragma unroll
  for (int kk = 0; kk < 2; ++kk)
    qf[kk] = *(const uint4*)&smem[(rg * 32 + lr) * 64 +
                                  (((c * 4 + kk * 2 + l5) ^ (lr & 7)) << 3)];

  f32x16 z16;
#pragma unroll
  for (int i = 0; i < 16; ++i) z16[i] = 0.f;

  f32x16 O[2];   // O^T: rows = d (dblock*32 block), col = own q-row
  O[0] = z16; O[1] = z16;
  float rs = 0.f;

  for (int kv = 0; kv < SEQLEN; kv += 64) {
    __syncthreads();  // prev iter's Ks/Vt reads done (guards Q reads on iter 0)
#pragma unroll
    for (int ro = 0; ro < 2; ++ro) {
      int ft = ro * 256 + t;
      int row = ft >> 3;
      int col = (((ft & 7) ^ (row & 7)) << 3);
      async16(kbase + (kv + row) * 1024 + col, &smem[ft * 8]);
      async16(vbase + row * 2048 + kv + col, &smem[4096 + ft * 8]);
    }
    __syncthreads();  // staged data visible

    // V^T A-frags: Vt[d = db*32+lr][key = kc*16 + l5*8 + j]
    uint4 vf[2][4];
#pragma unroll
    for (int db = 0; db < 2; ++db)
#pragma unroll
      for (int kc = 0; kc < 4; ++kc)
        vf[db][kc] = *(const uint4*)&smem[4096 + (db * 32 + lr) * 64 +
                                          (((kc * 2 + l5) ^ (lr & 7)) << 3)];

#pragma unroll
    for (int kb2 = 0; kb2 < 2; ++kb2) {
      // S^T for 32 keys x 32 qrows of component c (first MFMA consumes z16)
      uint4 kf0 = *(const uint4*)&smem[(kb2 * 32 + lr) * 64 +
                                       (((c * 4 + l5) ^ (lr & 7)) << 3)];
      uint4 kf1 = *(const uint4*)&smem[(kb2 * 32 + lr) * 64 +
                                       (((c * 4 + 2 + l5) ^ (lr & 7)) << 3)];
      f32x16 s = mfma32(kf0, qf[0], z16);
      s = mfma32(kf1, qf[1], s);
      // exp2, truncate-pack to bf16 pairs; pk[2g+i] = keys 8g+4*l5+2i+{0,1}
      uint32_t pk[8];
      float rloc = 0.f;
#pragma unroll
      for (int g = 0; g < 4; ++g) {
        float e0 = fast_exp2(s[g * 4 + 0]);
        float e1 = fast_exp2(s[g * 4 + 1]);
        float e2 = fast_exp2(s[g * 4 + 2]);
        float e3 = fast_exp2(s[g * 4 + 3]);
        float s01 = e0 + e1, s23 = e2 + e3;   // pairwise for v_pk_add lowering
        rloc += s01 + s23;
        pk[2 * g]     = __builtin_amdgcn_perm(__builtin_bit_cast(uint32_t, e1),
                                              __builtin_bit_cast(uint32_t, e0),
                                              0x07060302u);
        pk[2 * g + 1] = __builtin_amdgcn_perm(__builtin_bit_cast(uint32_t, e3),
                                              __builtin_bit_cast(uint32_t, e2),
                                              0x07060302u);
      }
      rs += rloc;
      // assemble P^T B-frags (k-chunk t2: keys kb2*32 + t2*16 + l5*8 + j)
      // and run PV immediately
#pragma unroll
      for (int t2 = 0; t2 < 2; ++t2) {
        uint32_t s0 = hi ? pk[4 * t2]     : pk[4 * t2 + 2];
        uint32_t s1 = hi ? pk[4 * t2 + 1] : pk[4 * t2 + 3];
        uint32_t r0 = (uint32_t)__shfl_xor((int)s0, 32);
        uint32_t r1 = (uint32_t)__shfl_xor((int)s1, 32);
        uint4 bfr;
        bfr.x = hi ? r0 : pk[4 * t2];
        bfr.y = hi ? r1 : pk[4 * t2 + 1];
        bfr.z = hi ? pk[4 * t2 + 2] : r0;
        bfr.w = hi ? pk[4 * t2 + 3] : r1;
        O[0] = mfma32(vf[0][kb2 * 2 + t2], bfr, O[0]);
        O[1] = mfma32(vf[1][kb2 * 2 + t2], bfr, O[1]);
      }
    }
  }

  // ------------------- epilogue -------------------
  rs += __shfl_xor(rs, 32);          // full denominator for q-row rg*32+lr
  const int row64 = rg * 32 + lr;
  float* ex = (float*)smem;          // 64 qrows x 64 d, 16B-chunk swizzled
  __syncthreads();                   // last iter's smem reads complete

  if (c == 1) {
    float inv2 = (*lam_p) / rs;
#pragma unroll
    for (int db = 0; db < 2; ++db)
#pragma unroll
      for (int g = 0; g < 4; ++g) {
        int d0 = db * 32 + 8 * g + 4 * l5;
        int ch = (d0 >> 2) ^ (lr & 7);
        float4 v;
        v.x = O[db][4 * g + 0] * inv2;
        v.y = O[db][4 * g + 1] * inv2;
        v.z = O[db][4 * g + 2] * inv2;
        v.w = O[db][4 * g + 3] * inv2;
        *(float4*)&ex[row64 * 64 + ch * 4] = v;
      }
  }
  __syncthreads();
  if (c == 0) {
    float inv1 = 1.f / rs;
    float4 a4[8];
    float ssq = 0.f;
#pragma unroll
    for (int db = 0; db < 2; ++db)
#pragma unroll
      for (int g = 0; g < 4; ++g) {
        int d0 = db * 32 + 8 * g + 4 * l5;
        int ch = (d0 >> 2) ^ (lr & 7);
        float4 o2 = *(const float4*)&ex[row64 * 64 + ch * 4];
        float4 v;
        v.x = O[db][4 * g + 0] * inv1 - o2.x;
        v.y = O[db][4 * g + 1] * inv1 - o2.y;
        v.z = O[db][4 * g + 2] * inv1 - o2.z;
        v.w = O[db][4 * g + 3] * inv1 - o2.w;
        ssq += v.x * v.x + v.y * v.y + v.z * v.z + v.w * v.w;
        a4[db * 4 + g] = v;
      }
    ssq += __shfl_xor(ssq, 32);      // partner lane holds the other 32 dims
    float sc = rsqrtf(ssq * (1.f / 64.f) + 1e-5f) * ONE_MINUS_LI;
    const int rowg = tok0 + row64;
#pragma unroll
    for (int db = 0; db < 2; ++db)
#pragma unroll
      for (int g = 0; g < 4; ++g) {
        int d0 = db * 32 + 8 * g + 4 * l5;
        float4 wv = *(const float4*)&rmsw[d0];
        float4 v = a4[db * 4 + g];
        ushort4 pq;
        pq.x = f2bf(v.x * sc * wv.x);
        pq.y = f2bf(v.y * sc * wv.y);
        pq.z = f2bf(v.z * sc * wv.z);
        pq.w = f2bf(v.w * sc * wv.w);
        *(ushort4*)&ab[rowg * 1024 + hch + d0] = pq;
      }
  }
}

// ---------------------------------------------------------------------------
extern "C" void kernel_launch(void* const* d_in, const int* in_sizes, int n_in,
                              void* d_out, int out_size, void* d_ws, size_t ws_size,
                              hipStream_t stream)
{
  (void)in_sizes; (void)n_in; (void)out_size; (void)ws_size;
  const float* x    = (const float*)d_in[0];
  const float* Wq   = (const float*)d_in[1];
  const float* Wk   = (const float*)d_in[2];
  const float* Wv   = (const float*)d_in[3];
  const float* Wo   = (const float*)d_in[4];
  const float* lq1  = (const float*)d_in[5];
  const float* lk1  = (const float*)d_in[6];
  const float* lq2  = (const float*)d_in[7];
  const float* lk2  = (const float*)d_in[8];
  const float* rmsw = (const float*)d_in[9];
  float* out = (float*)d_out;

  char* ws = (char*)d_ws;
  u16* xb   = (u16*)(ws + 0);
  u16* wqb  = (u16*)(ws + 8388608);
  u16* wkb  = (u16*)(ws + 10485760);
  u16* wvb  = (u16*)(ws + 12582912);
  u16* wob  = (u16*)(ws + 14680064);
  u16* qb   = (u16*)(ws + 16777216);
  u16* kb   = (u16*)(ws + 25165824);
  u16* vtb  = (u16*)(ws + 33554432);   // V^T: [b][h][64 dims][2048 keys]
  u16* ab   = (u16*)(ws + 41943040);
  float* lam = (float*)(ws + 50331648);

  hipLaunchKernelGGL(prep_kernel, dim3(8192), dim3(256), 0, stream,
                     x, Wq, Wk, Wv, Wo, lq1, lk1, lq2, lk2,
                     xb, wqb, wkb, wvb, wob, lam);
  hipLaunchKernelGGL(gemm_qkv_kernel, dim3(8, 32, 3), dim3(256), 0, stream,
                     xb, wqb, wkb, wvb, qb, kb, vtb);
  hipLaunchKernelGGL(attn_kernel, dim3(32, 16, 2), dim3(256), 0, stream,
                     qb, kb, vtb, lam, rmsw, ab);
  hipLaunchKernelGGL(gemm_out_kernel, dim3(8, 32), dim3(256), 0, stream,
                     ab, wob, out);
}

// Round 7
// 231.163 us; speedup vs baseline: 1.0855x; 1.0855x over previous
//
#include <hip/hip_runtime.h>
#include <stdint.h>

typedef unsigned short u16;
typedef __bf16 bf16x8 __attribute__((ext_vector_type(8)));
typedef float f32x4 __attribute__((ext_vector_type(4)));
typedef float f32x16 __attribute__((ext_vector_type(16)));
typedef unsigned uint2v __attribute__((ext_vector_type(2)));

#define TOKENS 4096
#define SEQLEN 2048
#define EMB 1024
#define NHEADS 16

static constexpr float LAMBDA_INIT_F = 0.7836057665316245f;   // 0.8 - 0.6*exp(-3.6)
static constexpr float ONE_MINUS_LI  = 0.21639423346837553f;
static constexpr float SCALE_F       = 0.17677669529663687f;  // 32^-0.5
static constexpr float LOG2E_F       = 1.4426950408889634f;

__device__ __forceinline__ u16 f2bf(float f) {
  uint32_t u = __builtin_bit_cast(uint32_t, f);
  u += 0x7fffu + ((u >> 16) & 1u);
  return (u16)(u >> 16);
}
__device__ __forceinline__ float bf2f(u16 h) {
  uint32_t u = ((uint32_t)h) << 16;
  return __builtin_bit_cast(float, u);
}
__device__ __forceinline__ float fast_exp2(float x) {
#if __has_builtin(__builtin_amdgcn_exp2f)
  return __builtin_amdgcn_exp2f(x);
#else
  return exp2f(x);
#endif
}
__device__ __forceinline__ void async16(const void* g, void* l) {
  __builtin_amdgcn_global_load_lds((__attribute__((address_space(1))) void*)(g),
                                   (__attribute__((address_space(3))) void*)(l),
                                   16, 0, 0);
}
__device__ __forceinline__ f32x4 mfma16(uint4 a, uint4 b, f32x4 c) {
  return __builtin_amdgcn_mfma_f32_16x16x32_bf16(
      __builtin_bit_cast(bf16x8, a), __builtin_bit_cast(bf16x8, b), c, 0, 0, 0);
}
__device__ __forceinline__ f32x16 mfma32(uint4 a, uint4 b, f32x16 c) {
  return __builtin_amdgcn_mfma_f32_32x32x16_bf16(
      __builtin_bit_cast(bf16x8, a), __builtin_bit_cast(bf16x8, b), c, 0, 0, 0);
}

// ---------------------------------------------------------------------------
// prep: fp32 -> bf16 for x, Wq, Wk, Wv, Wo; compute lam scalar.
// ---------------------------------------------------------------------------
__global__ __launch_bounds__(256) void prep_kernel(
    const float* __restrict__ x,  const float* __restrict__ wq,
    const float* __restrict__ wk, const float* __restrict__ wv,
    const float* __restrict__ wo, const float* __restrict__ lq1,
    const float* __restrict__ lk1,const float* __restrict__ lq2,
    const float* __restrict__ lk2,
    u16* __restrict__ xb, u16* __restrict__ wqb, u16* __restrict__ wkb,
    u16* __restrict__ wvb, u16* __restrict__ wob, float* __restrict__ lam_out)
{
  int i0 = (blockIdx.x * 256 + threadIdx.x) * 4;
  const float* src; u16* dst; int j;
  if (i0 < 4194304)      { src = x;  dst = xb;  j = i0; }
  else if (i0 < 5242880) { src = wq; dst = wqb; j = i0 - 4194304; }
  else if (i0 < 6291456) { src = wk; dst = wkb; j = i0 - 5242880; }
  else if (i0 < 7340032) { src = wv; dst = wvb; j = i0 - 6291456; }
  else                   { src = wo; dst = wob; j = i0 - 7340032; }
  float4 v = *(const float4*)(src + j);
  uint2 pack;
  pack.x = (uint32_t)f2bf(v.x) | ((uint32_t)f2bf(v.y) << 16);
  pack.y = (uint32_t)f2bf(v.z) | ((uint32_t)f2bf(v.w) << 16);
  *(uint2*)(dst + j) = pack;

  if (blockIdx.x == 0 && threadIdx.x == 0) {
    float d1 = 0.f, d2 = 0.f;
    for (int i = 0; i < 32; ++i) { d1 += lq1[i] * lk1[i]; d2 += lq2[i] * lk2[i]; }
    *lam_out = expf(d1) - expf(d2) + LAMBDA_INIT_F;
  }
}

// ---------------------------------------------------------------------------
// GEMM: C(4096x1024) = A(4096x1024,bf16) * B^T (B is 1024x1024 N-major, bf16)
// 128x128 block tile, BK=64, 4 waves each 64x64, 16x16x32 bf16 MFMA.
// LDS XOR-swizzled (16B chunk ^= row&7) to kill 128B-stride bank conflicts.
// MODE: 0 = bf16 row-major C, 1 = f32 row-major C, 2 = bf16 V^T [b][h][d][key]
// NOTE: RoPE fusion into this epilogue was tried (R5/R6) and cost +13us on
// gemm_qkv (occupancy/VGPR pressure) -- keep rope as a separate kernel.
// ---------------------------------------------------------------------------
template <int MODE>
__device__ __forceinline__ void gemm_body(const u16* __restrict__ A,
                                          const u16* __restrict__ B,
                                          void* __restrict__ C)
{
  __shared__ u16 As[128 * 64];
  __shared__ u16 Bs[128 * 64];
  const int t = threadIdx.x;
  const int lane = t & 63, w = t >> 6;
  const int q4 = lane >> 4, lm = lane & 15;
  const int wr = w >> 1, wc = w & 1;
  const int bm = blockIdx.y * 128, bn = blockIdx.x * 128;

  f32x4 acc[4][4];
#pragma unroll
  for (int mi = 0; mi < 4; ++mi)
#pragma unroll
    for (int ni = 0; ni < 4; ++ni) acc[mi][ni] = (f32x4){0.f, 0.f, 0.f, 0.f};

  for (int kt = 0; kt < 16; ++kt) {
    const int k0 = kt * 64;
    __syncthreads();  // previous tile's LDS reads complete
#pragma unroll
    for (int ro = 0; ro < 4; ++ro) {
      int ft = ro * 256 + t;
      int row = ft >> 3;
      int col = (((ft & 7) ^ (row & 7)) << 3);   // source chunk permuted = XOR swizzle
      async16(&A[(bm + row) * 1024 + k0 + col], &As[ft * 8]);
      async16(&B[(bn + row) * 1024 + k0 + col], &Bs[ft * 8]);
    }
    __syncthreads();  // drains vmcnt -> LDS visible
#pragma unroll
    for (int ks = 0; ks < 2; ++ks) {
      uint4 af[4], bf[4];
#pragma unroll
      for (int mi = 0; mi < 4; ++mi)
        af[mi] = *(const uint4*)&As[(wr * 64 + mi * 16 + lm) * 64 +
                                    (((ks * 4 + q4) ^ (lm & 7)) << 3)];
#pragma unroll
      for (int ni = 0; ni < 4; ++ni)
        bf[ni] = *(const uint4*)&Bs[(wc * 64 + ni * 16 + lm) * 64 +
                                    (((ks * 4 + q4) ^ (lm & 7)) << 3)];
#pragma unroll
      for (int mi = 0; mi < 4; ++mi)
#pragma unroll
        for (int ni = 0; ni < 4; ++ni)
          acc[mi][ni] = mfma16(af[mi], bf[ni], acc[mi][ni]);
    }
  }
#pragma unroll
  for (int mi = 0; mi < 4; ++mi)
#pragma unroll
    for (int ni = 0; ni < 4; ++ni) {
      if (MODE == 2) {
        // V^T: rows of C are tokens, cols are channels; write vt[b][h][d][key]
        int token0 = bm + wr * 64 + mi * 16 + q4 * 4;     // 4 consecutive tokens
        int col = bn + wc * 64 + ni * 16 + lm;            // channel 0..1023
        int bb = token0 >> 11, key0 = token0 & 2047;
        int h = col >> 6, d = col & 63;
        ushort4 pk;
        pk.x = f2bf(acc[mi][ni][0]);
        pk.y = f2bf(acc[mi][ni][1]);
        pk.z = f2bf(acc[mi][ni][2]);
        pk.w = f2bf(acc[mi][ni][3]);
        *(ushort4*)((u16*)C + ((size_t)((bb * 16 + h) * 64 + d)) * 2048 + key0) = pk;
      } else {
#pragma unroll
        for (int r = 0; r < 4; ++r) {
          int row = bm + wr * 64 + mi * 16 + q4 * 4 + r;
          int col = bn + wc * 64 + ni * 16 + lm;
          if (MODE == 1) ((float*)C)[row * 1024 + col] = acc[mi][ni][r];
          else           ((u16*)C)[row * 1024 + col]   = f2bf(acc[mi][ni][r]);
        }
      }
    }
}

__global__ __launch_bounds__(256) void gemm_qkv_kernel(
    const u16* __restrict__ xb, const u16* __restrict__ wqb,
    const u16* __restrict__ wkb, const u16* __restrict__ wvb,
    u16* __restrict__ qb, u16* __restrict__ kb, u16* __restrict__ vtb)
{
  if (blockIdx.z == 0)      gemm_body<0>(xb, wqb, qb);
  else if (blockIdx.z == 1) gemm_body<0>(xb, wkb, kb);
  else                      gemm_body<2>(xb, wvb, vtb);
}

__global__ __launch_bounds__(256) void gemm_out_kernel(
    const u16* __restrict__ ab, const u16* __restrict__ wob,
    float* __restrict__ out)
{
  gemm_body<1>(ab, wob, out);
}

// ---------------------------------------------------------------------------
// RoPE (interleaved pairs within each 32-dim head), in place on bf16 q,k.
// Folds SCALE * log2(e) into q (attention uses exp2).
// ---------------------------------------------------------------------------
__global__ __launch_bounds__(256) void rope_kernel(u16* __restrict__ qb,
                                                   u16* __restrict__ kb)
{
  int p = blockIdx.x * 256 + threadIdx.x;  // pair index, 0..4096*512-1
  int tok = p >> 9;
  int pc = p & 511;          // channel pair: channel = 2*pc
  int j = pc & 15;           // rotary frequency index within head
  int tpos = tok & (SEQLEN - 1);
  float ang = exp2f(-(float)j * 0.8858474919699633f);  // 10000^(-j/15)
  float f = (float)tpos * ang;
  float s, c;
  sincosf(f, &s, &c);
  u16* ptr = ((blockIdx.y == 0) ? qb : kb) + tok * 1024 + pc * 2;
  uint32_t u = *(const uint32_t*)ptr;
  float x1 = bf2f((u16)(u & 0xffff));
  float x2 = bf2f((u16)(u >> 16));
  float o1 = x1 * c - x2 * s;
  float o2 = x1 * s + x2 * c;
  if (blockIdx.y == 0) { o1 *= SCALE_F * LOG2E_F; o2 *= SCALE_F * LOG2E_F; }
  *(uint32_t*)ptr = (uint32_t)f2bf(o1) | ((uint32_t)f2bf(o2) << 16);
}

// ---------------------------------------------------------------------------
// Fused differential flash attention + RMS-norm epilogue.
// Block = (64-row Q tile, head, batch); 4 waves specialized as
// (component c = w>>1, rowgroup rg = w&1), each wave owns 32 q-rows x 1 comp.
// S^T = mfma32(K_frag, Q_frag): lane's C-column = its q-row, 16 keys in-lane.
// exp2 + v_perm-pack to bf16; the PV B-operand (P^T) half-exchange is done
// with v_permlane32_swap_b32 (gfx950 VALU op): swap(pk0,pk2) yields BOTH
// word0 (vdst: lo=local pk0, hi=remote pk2) and word2 (src: lo=remote pk0,
// hi=local pk2) -- replaces the ds_bpermute shfl_xor path that accounted for
// all 6.4e6 SQ_LDS_BANK_CONFLICT cycles.
// PV: O^T = mfma32(V^T A-frag, P^T B-frag); denominators are per-lane.
// LDS 16KB: Ks [0,4096) u16, Vt [4096,8192) u16, XOR-swizzled; reused for
// the f32 epilogue exchange and the pre-loop Q stage.
// ---------------------------------------------------------------------------
__global__ __launch_bounds__(256, 4) void attn_kernel(
    const u16* __restrict__ qb, const u16* __restrict__ kb,
    const u16* __restrict__ vtb, const float* __restrict__ lam_p,
    const float* __restrict__ rmsw, u16* __restrict__ ab)
{
  __shared__ u16 smem[8192];

  const int t = threadIdx.x;
  const int lane = t & 63, w = t >> 6;
  const int l5 = lane >> 5, lr = lane & 31;
  const int c = w >> 1, rg = w & 1;
  const bool hi = (l5 != 0);
  const int qt = blockIdx.x, h = blockIdx.y, b = blockIdx.z;
  const int tok0 = b * SEQLEN + qt * 64;
  const int hch = h * 64;

  const u16* kbase = kb + (size_t)(b * SEQLEN) * 1024 + hch;
  const u16* vbase = vtb + (size_t)((b * 16 + h) * 64) * 2048;

  // stage Q tile (64 rows x 64 ch) into Ks region, swizzled
#pragma unroll
  for (int ro = 0; ro < 2; ++ro) {
    int ft = ro * 256 + t;
    int row = ft >> 3;
    int col = (((ft & 7) ^ (row & 7)) << 3);
    async16(&qb[(tok0 + row) * 1024 + hch + col], &smem[ft * 8]);
  }
  __syncthreads();
  uint4 qf[2];   // B-frags for comp c: Q[qrow=rg*32+lr][c*32 + kk*16 + l5*8 + j]
#pragma unroll
  for (int kk = 0; kk < 2; ++kk)
    qf[kk] = *(const uint4*)&smem[(rg * 32 + lr) * 64 +
                                  (((c * 4 + kk * 2 + l5) ^ (lr & 7)) << 3)];

  f32x16 z16;
#pragma unroll
  for (int i = 0; i < 16; ++i) z16[i] = 0.f;

  f32x16 O[2];   // O^T: rows = d (dblock*32 block), col = own q-row
  O[0] = z16; O[1] = z16;
  float rs = 0.f;

  for (int kv = 0; kv < SEQLEN; kv += 64) {
    __syncthreads();  // prev iter's Ks/Vt reads done (guards Q reads on iter 0)
#pragma unroll
    for (int ro = 0; ro < 2; ++ro) {
      int ft = ro * 256 + t;
      int row = ft >> 3;
      int col = (((ft & 7) ^ (row & 7)) << 3);
      async16(kbase + (kv + row) * 1024 + col, &smem[ft * 8]);
      async16(vbase + row * 2048 + kv + col, &smem[4096 + ft * 8]);
    }
    __syncthreads();  // staged data visible

    // V^T A-frags: Vt[d = db*32+lr][key = kc*16 + l5*8 + j]
    uint4 vf[2][4];
#pragma unroll
    for (int db = 0; db < 2; ++db)
#pragma unroll
      for (int kc = 0; kc < 4; ++kc)
        vf[db][kc] = *(const uint4*)&smem[4096 + (db * 32 + lr) * 64 +
                                          (((kc * 2 + l5) ^ (lr & 7)) << 3)];

#pragma unroll
    for (int kb2 = 0; kb2 < 2; ++kb2) {
      // S^T for 32 keys x 32 qrows of component c (first MFMA consumes z16)
      uint4 kf0 = *(const uint4*)&smem[(kb2 * 32 + lr) * 64 +
                                       (((c * 4 + l5) ^ (lr & 7)) << 3)];
      uint4 kf1 = *(const uint4*)&smem[(kb2 * 32 + lr) * 64 +
                                       (((c * 4 + 2 + l5) ^ (lr & 7)) << 3)];
      f32x16 s = mfma32(kf0, qf[0], z16);
      s = mfma32(kf1, qf[1], s);
      // exp2, truncate-pack to bf16 pairs; pk[2g+i] = keys 8g+4*l5+2i+{0,1}
      uint32_t pk[8];
      float rloc = 0.f;
#pragma unroll
      for (int g = 0; g < 4; ++g) {
        float e0 = fast_exp2(s[g * 4 + 0]);
        float e1 = fast_exp2(s[g * 4 + 1]);
        float e2 = fast_exp2(s[g * 4 + 2]);
        float e3 = fast_exp2(s[g * 4 + 3]);
        float s01 = e0 + e1, s23 = e2 + e3;   // pairwise for v_pk_add lowering
        rloc += s01 + s23;
        pk[2 * g]     = __builtin_amdgcn_perm(__builtin_bit_cast(uint32_t, e1),
                                              __builtin_bit_cast(uint32_t, e0),
                                              0x07060302u);
        pk[2 * g + 1] = __builtin_amdgcn_perm(__builtin_bit_cast(uint32_t, e3),
                                              __builtin_bit_cast(uint32_t, e2),
                                              0x07060302u);
      }
      rs += rloc;
      // assemble P^T B-frags (k-chunk t2: keys kb2*32 + t2*16 + l5*8 + j)
#pragma unroll
      for (int t2 = 0; t2 < 2; ++t2) {
        uint4 bfr;
#if __has_builtin(__builtin_amdgcn_permlane32_swap)
        uint2v r02 = __builtin_amdgcn_permlane32_swap(pk[4 * t2],     pk[4 * t2 + 2],
                                                      false, false);
        uint2v r13 = __builtin_amdgcn_permlane32_swap(pk[4 * t2 + 1], pk[4 * t2 + 3],
                                                      false, false);
        bfr.x = r02.x;   // lo: local pk0, hi: remote pk2
        bfr.y = r13.x;   // lo: local pk1, hi: remote pk3
        bfr.z = r02.y;   // lo: remote pk0, hi: local pk2
        bfr.w = r13.y;   // lo: remote pk1, hi: local pk3
#else
        uint32_t s0 = hi ? pk[4 * t2]     : pk[4 * t2 + 2];
        uint32_t s1 = hi ? pk[4 * t2 + 1] : pk[4 * t2 + 3];
        uint32_t r0 = (uint32_t)__shfl_xor((int)s0, 32);
        uint32_t r1 = (uint32_t)__shfl_xor((int)s1, 32);
        bfr.x = hi ? r0 : pk[4 * t2];
        bfr.y = hi ? r1 : pk[4 * t2 + 1];
        bfr.z = hi ? pk[4 * t2 + 2] : r0;
        bfr.w = hi ? pk[4 * t2 + 3] : r1;
#endif
        O[0] = mfma32(vf[0][kb2 * 2 + t2], bfr, O[0]);
        O[1] = mfma32(vf[1][kb2 * 2 + t2], bfr, O[1]);
      }
    }
  }

  // ------------------- epilogue -------------------
  rs += __shfl_xor(rs, 32);          // full denominator for q-row rg*32+lr
  const int row64 = rg * 32 + lr;
  float* ex = (float*)smem;          // 64 qrows x 64 d, 16B-chunk swizzled
  __syncthreads();                   // last iter's smem reads complete

  if (c == 1) {
    float inv2 = (*lam_p) / rs;
#pragma unroll
    for (int db = 0; db < 2; ++db)
#pragma unroll
      for (int g = 0; g < 4; ++g) {
        int d0 = db * 32 + 8 * g + 4 * l5;
        int ch = (d0 >> 2) ^ (lr & 7);
        float4 v;
        v.x = O[db][4 * g + 0] * inv2;
        v.y = O[db][4 * g + 1] * inv2;
        v.z = O[db][4 * g + 2] * inv2;
        v.w = O[db][4 * g + 3] * inv2;
        *(float4*)&ex[row64 * 64 + ch * 4] = v;
      }
  }
  __syncthreads();
  if (c == 0) {
    float inv1 = 1.f / rs;
    float4 a4[8];
    float ssq = 0.f;
#pragma unroll
    for (int db = 0; db < 2; ++db)
#pragma unroll
      for (int g = 0; g < 4; ++g) {
        int d0 = db * 32 + 8 * g + 4 * l5;
        int ch = (d0 >> 2) ^ (lr & 7);
        float4 o2 = *(const float4*)&ex[row64 * 64 + ch * 4];
        float4 v;
        v.x = O[db][4 * g + 0] * inv1 - o2.x;
        v.y = O[db][4 * g + 1] * inv1 - o2.y;
        v.z = O[db][4 * g + 2] * inv1 - o2.z;
        v.w = O[db][4 * g + 3] * inv1 - o2.w;
        ssq += v.x * v.x + v.y * v.y + v.z * v.z + v.w * v.w;
        a4[db * 4 + g] = v;
      }
    ssq += __shfl_xor(ssq, 32);      // partner lane holds the other 32 dims
    float sc = rsqrtf(ssq * (1.f / 64.f) + 1e-5f) * ONE_MINUS_LI;
    const int rowg = tok0 + row64;
#pragma unroll
    for (int db = 0; db < 2; ++db)
#pragma unroll
      for (int g = 0; g < 4; ++g) {
        int d0 = db * 32 + 8 * g + 4 * l5;
        float4 wv = *(const float4*)&rmsw[d0];
        float4 v = a4[db * 4 + g];
        ushort4 pq;
        pq.x = f2bf(v.x * sc * wv.x);
        pq.y = f2bf(v.y * sc * wv.y);
        pq.z = f2bf(v.z * sc * wv.z);
        pq.w = f2bf(v.w * sc * wv.w);
        *(ushort4*)&ab[rowg * 1024 + hch + d0] = pq;
      }
  }
}

// ---------------------------------------------------------------------------
extern "C" void kernel_launch(void* const* d_in, const int* in_sizes, int n_in,
                              void* d_out, int out_size, void* d_ws, size_t ws_size,
                              hipStream_t stream)
{
  (void)in_sizes; (void)n_in; (void)out_size; (void)ws_size;
  const float* x    = (const float*)d_in[0];
  const float* Wq   = (const float*)d_in[1];
  const float* Wk   = (const float*)d_in[2];
  const float* Wv   = (const float*)d_in[3];
  const float* Wo   = (const float*)d_in[4];
  const float* lq1  = (const float*)d_in[5];
  const float* lk1  = (const float*)d_in[6];
  const float* lq2  = (const float*)d_in[7];
  const float* lk2  = (const float*)d_in[8];
  const float* rmsw = (const float*)d_in[9];
  float* out = (float*)d_out;

  char* ws = (char*)d_ws;
  u16* xb   = (u16*)(ws + 0);
  u16* wqb  = (u16*)(ws + 8388608);
  u16* wkb  = (u16*)(ws + 10485760);
  u16* wvb  = (u16*)(ws + 12582912);
  u16* wob  = (u16*)(ws + 14680064);
  u16* qb   = (u16*)(ws + 16777216);
  u16* kb   = (u16*)(ws + 25165824);
  u16* vtb  = (u16*)(ws + 33554432);   // V^T: [b][h][64 dims][2048 keys]
  u16* ab   = (u16*)(ws + 41943040);
  float* lam = (float*)(ws + 50331648);

  hipLaunchKernelGGL(prep_kernel, dim3(8192), dim3(256), 0, stream,
                     x, Wq, Wk, Wv, Wo, lq1, lk1, lq2, lk2,
                     xb, wqb, wkb, wvb, wob, lam);
  hipLaunchKernelGGL(gemm_qkv_kernel, dim3(8, 32, 3), dim3(256), 0, stream,
                     xb, wqb, wkb, wvb, qb, kb, vtb);
  hipLaunchKernelGGL(rope_kernel, dim3(8192, 2), dim3(256), 0, stream, qb, kb);
  hipLaunchKernelGGL(attn_kernel, dim3(32, 16, 2), dim3(256), 0, stream,
                     qb, kb, vtb, lam, rmsw, ab);
  hipLaunchKernelGGL(gemm_out_kernel, dim3(8, 32), dim3(256), 0, stream,
                     ab, wob, out);
}